// Round 22
// baseline (181.870 us; speedup 1.0000x reference)
//
#include <hip/hip_runtime.h>

typedef unsigned short u16;
typedef short bf16x8 __attribute__((ext_vector_type(8)));
typedef float f32x4 __attribute__((ext_vector_type(4)));
typedef unsigned int u32;
typedef u32 u32x4 __attribute__((ext_vector_type(4)));

#define B_ 4
#define S_ 2048
#define D_ 1024
#define H_ 16
#define DH_ 64
#define M_ 8192   // B*S
#define SCL2E 0.1803368801111244f  /* 0.125 * log2(e), folded into Q at gemm1 */

__device__ __forceinline__ u16 f2b(float f) {
  union { float f; unsigned int u; } v; v.f = f;
  unsigned int u = v.u;
  unsigned int r = (u + 0x7FFFu + ((u >> 16) & 1u)) >> 16;
  return (u16)r;
}

// async global->LDS, 16B per lane; lds dst is wave-uniform base + lane*16
__device__ __forceinline__ void gload16(const void* g, void* l) {
  __builtin_amdgcn_global_load_lds(
      (const __attribute__((address_space(1))) unsigned int*)g,
      (__attribute__((address_space(3))) unsigned int*)l,
      16, 0, 0);
}

// pack two f32 -> two bf16 (RNE) in one VALU op
__device__ __forceinline__ u32 cvt_pk_bf16(float lo, float hi) {
  u32 r;
  asm("v_cvt_pk_bf16_f32 %0, %1, %2" : "=v"(r) : "v"(lo), "v"(hi));
  return r;
}

// exp2 as a single v_exp_f32
__device__ __forceinline__ float fexp2(float x) {
  float r;
  asm("v_exp_f32 %0, %1" : "=v"(r) : "v"(x));
  return r;
}

// ---------------- fused preprocessing: one kernel, three block ranges ----------------
struct __attribute__((aligned(8))) u16x4 { u16 x, y, z, w; };

__global__ __launch_bounds__(256) void prep_fused(
    const float* __restrict__ x, u16* __restrict__ xb,
    const float* __restrict__ w1, u16* __restrict__ w1t,
    const float* __restrict__ w2, u16* __restrict__ w2t) {
  __shared__ float tile[32][33];
  const int bid = blockIdx.x, t = threadIdx.x;

  if (bid < 2048) {
    const int n = M_ * D_;
    for (int i = (bid * 256 + t) * 4; i < n; i += 2048 * 256 * 4) {
      float4 v = *(const float4*)(x + i);
      u16x4 o; o.x = f2b(v.x); o.y = f2b(v.y); o.z = f2b(v.z); o.w = f2b(v.w);
      *(u16x4*)(xb + i) = o;
    }
    return;
  }

  const float* in;  u16* outp;  int R, C, bx, by;
  if (bid < 5120) {
    int rel = bid - 2048; bx = rel % 96; by = rel / 96;
    in = w1; outp = w1t; R = 1024; C = 3072;
  } else {
    int rel = bid - 5120; bx = rel % 32; by = rel / 32;
    in = w2; outp = w2t; R = 1024; C = 1024;
  }
  const int c0 = bx * 32, r0 = by * 32;
  const int tx = t & 31, ty = t >> 5;   // 32 x 8
#pragma unroll
  for (int j = 0; j < 32; j += 8)
    tile[ty + j][tx] = in[(size_t)(r0 + ty + j) * C + c0 + tx];
  __syncthreads();
#pragma unroll
  for (int j = 0; j < 32; j += 8)
    outp[(size_t)(c0 + ty + j) * R + r0 + tx] = f2b(tile[tx][ty + j]);
}

// ---------------- in-place V repack: apply dh-XOR chunk permutation ----------------
__global__ __launch_bounds__(256) void repack_v(u16* __restrict__ vtb) {
  const int c = blockIdx.x * 256 + threadIdx.x;     // [0, 1<<20)
  const int g = c & 15;
  const int x = (c >> 8) & 15;                      // dh & 15
  const int gp = g ^ x;
  if (g >= gp) return;                              // identity rows / partner
  u16* base = vtb + (size_t)(c >> 8) * 2048 + ((c >> 4) & 15) * 128;
  bf16x8 a = *(bf16x8*)(base + g * 8);
  bf16x8 b = *(bf16x8*)(base + gp * 8);
  *(bf16x8*)(base + g * 8) = b;
  *(bf16x8*)(base + gp * 8) = a;
}

// ---------------- bf16 GEMM: A[M][K] @ BT[N][K]^T + bias ----------------
// BK=32 variant of the proven counted-vmcnt 2-phase template: 4-wave 128x128,
// LDS 32 KB (2 dbuf x 8 KB x 2 ops) -> 4 blocks/CU = 16 waves/CU (TLP lever).
// Per K-tile: STAGE(nxt) 4 gloads/wave, vmcnt(4), raw barrier publish,
// 8 ds_read_b128 (4-slot XOR, 4-way conflict accepted) + 16 MFMA, raw barrier.
// MODE 0: fp32 out. MODE 1: qkv scatter — Q pre-scaled; K pre-swizzled
// (dh' = dh ^ ((s&7)<<3)); V^T slot-permuted ONLY (dh-XOR applied by repack_v).
template <int MODE>
__global__ __launch_bounds__(256) void gemm_bt(
    const u16* __restrict__ A, const u16* __restrict__ BT,
    const float* __restrict__ bias, float* __restrict__ outf,
    u16* __restrict__ qb, u16* __restrict__ kb, u16* __restrict__ vtb,
    int Ncols, int Kdim) {
  __shared__ __attribute__((aligned(16))) u16 lsA[2][128 * 32];
  __shared__ __attribute__((aligned(16))) u16 lsB[2][128 * 32];
  const int t = threadIdx.x;
  const int lane = t & 63, w = t >> 6;
  const int lhi = lane >> 4, llo = lane & 15;

  const int gx = gridDim.x;
  const int lin = blockIdx.y * gx + blockIdx.x;
  const int nwg = gx * gridDim.y;
  const int sw = (lin & 7) * (nwg >> 3) + (lin >> 3);
  const int m0 = (sw / gx) * 128, n0 = (sw % gx) * 128;

  const int wr = (w >> 1) * 64, wc = (w & 1) * 64;

  // staging geometry: call j covers rows w*32 + j*16 + r4, 4 lanes/row.
  // source col pre-XOR'd by row&3 so linear LDS + XOR read = correct data.
  const int r4 = lane >> 2;                       // row within 16-row group
  const int scolE = ((lane & 3) ^ (r4 & 3)) * 8;  // global col (elems)

  f32x4 acc[4][4] = {};
  const int nt = Kdim >> 5;                       // BK=32

#define STAGE_G(buf, kk0)                                                        \
  _Pragma("unroll") for (int j = 0; j < 2; ++j) {                                \
    gload16(A + (size_t)(m0 + w * 32 + j * 16 + r4) * Kdim + (kk0) + scolE,      \
            &lsA[buf][(w * 32 + j * 16) * 32]);                                  \
    gload16(BT + (size_t)(n0 + w * 32 + j * 16 + r4) * Kdim + (kk0) + scolE,     \
            &lsB[buf][(w * 32 + j * 16) * 32]);                                  \
  }

  STAGE_G(0, 0)                       // 4 loads/wave in flight

  for (int tt = 0; tt < nt; ++tt) {
    const int cur = tt & 1;
    if (tt + 1 < nt) {
      STAGE_G(cur ^ 1, (tt + 1) << 5)                     // +4 newer loads
      asm volatile("s_waitcnt vmcnt(4)" ::: "memory");    // own cur loads done
    } else {
      asm volatile("s_waitcnt vmcnt(0)" ::: "memory");
    }
    __builtin_amdgcn_sched_barrier(0);
    __builtin_amdgcn_s_barrier();     // publish cur tile (no drain)
    __builtin_amdgcn_sched_barrier(0);
    {
      bf16x8 af[4], bfr[4];
#pragma unroll
      for (int i = 0; i < 4; ++i) {
        int ra = wr + i * 16 + llo;
        af[i] = *(const bf16x8*)((const char*)&lsA[cur][ra * 32] +
                                 ((lhi * 16) ^ ((ra & 3) << 4)));
        int rb = wc + i * 16 + llo;
        bfr[i] = *(const bf16x8*)((const char*)&lsB[cur][rb * 32] +
                                  ((lhi * 16) ^ ((rb & 3) << 4)));
      }
#pragma unroll
      for (int mi = 0; mi < 4; ++mi)
#pragma unroll
        for (int ni = 0; ni < 4; ++ni)
          acc[mi][ni] = __builtin_amdgcn_mfma_f32_16x16x32_bf16(af[mi], bfr[ni], acc[mi][ni], 0, 0, 0);
    }
    __builtin_amdgcn_sched_barrier(0);
    __builtin_amdgcn_s_barrier();     // reads of cur done before next overwrite
  }
#undef STAGE_G

  if (MODE == 0) {
#pragma unroll
    for (int mi = 0; mi < 4; ++mi)
#pragma unroll
      for (int ni = 0; ni < 4; ++ni)
#pragma unroll
        for (int r = 0; r < 4; ++r) {
          int m = m0 + wr + mi * 16 + lhi * 4 + r;
          int n = n0 + wc + ni * 16 + llo;
          outf[(size_t)m * Ncols + n] = acc[mi][ni][r] + bias[n];
        }
  } else if (n0 < 1024) {            // Q (pre-scaled)
#pragma unroll
    for (int mi = 0; mi < 4; ++mi)
#pragma unroll
      for (int ni = 0; ni < 4; ++ni)
#pragma unroll
        for (int r = 0; r < 4; ++r) {
          int m = m0 + wr + mi * 16 + lhi * 4 + r;
          int n = n0 + wc + ni * 16 + llo;
          int bidx = m >> 11, s = m & 2047, hh = n >> 6, dh = n & 63;
          qb[((size_t)(bidx * 16 + hh) * 2048 + s) * 64 + dh] =
              f2b((acc[mi][ni][r] + bias[n]) * SCL2E);
        }
  } else if (n0 < 2048) {            // K, pre-swizzled for attn direct gload
#pragma unroll
    for (int mi = 0; mi < 4; ++mi)
#pragma unroll
      for (int ni = 0; ni < 4; ++ni)
#pragma unroll
        for (int r = 0; r < 4; ++r) {
          int m = m0 + wr + mi * 16 + lhi * 4 + r;
          int n2 = n0 - 1024 + wc + ni * 16 + llo;
          int bidx = m >> 11, s = m & 2047, hh = n2 >> 6;
          int dh = (n2 & 63) ^ ((s & 7) << 3);
          kb[((size_t)(bidx * 16 + hh) * 2048 + s) * 64 + dh] =
              f2b(acc[mi][ni][r] + bias[n0 + wc + ni * 16 + llo]);
        }
  } else {                           // V^T, slot-permuted ONLY (fast store)
#pragma unroll
    for (int mi = 0; mi < 4; ++mi)
#pragma unroll
      for (int ni = 0; ni < 4; ++ni)
#pragma unroll
        for (int r = 0; r < 4; ++r) {
          int m = m0 + wr + mi * 16 + lhi * 4 + r;
          int n2 = n0 - 2048 + wc + ni * 16 + llo;
          int bidx = m >> 11, s = m & 2047, hh = n2 >> 6, dh = n2 & 63;
          int col = (s & ~127) | ((s & 15) * 8 + ((s >> 4) & 7));
          vtb[((size_t)(bidx * 16 + hh) * 64 + dh) * 2048 + col] =
              f2b(acc[mi][ni][r] + bias[n0 + wc + ni * 16 + llo]);
        }
  }
}

// ---------------- flash-style causal attention, 8-wave blocks (r20 best config) ----------------
// K double-buffered + V single-buffered, BOTH staged direct via global_load_lds
// from pre-swizzled global (K by gemm1, V by repack_v). XOR'd conflict-free
// reads. P unpadded row-XOR. exp2 via v_exp_f32; row-sum via ones-MFMA.
// LDS = 32(K dbuf) + 16(V) + 32(P) = 80 KB -> 2 blocks/CU.
__global__ __launch_bounds__(512) void attn128(
    const u16* __restrict__ Qb, const u16* __restrict__ Kb,
    const u16* __restrict__ VTb, u16* __restrict__ AO) {
  __shared__ __attribute__((aligned(16))) u16 kls[2][128 * 64]; // K tiles (dbuf)
  __shared__ __attribute__((aligned(16))) u16 vls[64 * 128];    // V^T tile
  __shared__ __attribute__((aligned(16))) u16 pl[8][16][128];   // P, row-XOR swizzled
  const int t = threadIdx.x, w = t >> 6, lane = t & 63;
  const int lhi = lane >> 4, llo = lane & 15;

  // XCD-grouping swizzle (bijective): all 8 pr-blocks of a head share one XCD
  const int lin = blockIdx.y * 8 + blockIdx.x;
  const int bh = ((lin >> 6) << 3) | (lin & 7);
  const int pr = (lin >> 3) & 7;
  const int bb = bh >> 4, hh = bh & 15;

  const u16* Qp = Qb + (size_t)bh * (S_ * DH_);
  const u16* Kp = Kb + (size_t)bh * (S_ * DH_);
  const u16* Vp = VTb + (size_t)bh * (DH_ * S_);

  bf16x8 ones;
#pragma unroll
  for (int i = 0; i < 8; ++i) ones[i] = (short)0x3F80;

#define STAGE_K(buf, kv0) {                                           \
    const u16* s_ = Kp + (size_t)(kv0) * 64 + t * 8;                  \
    gload16(s_,        &kls[buf][w * 512]);                           \
    gload16(s_ + 4096, &kls[buf][4096 + w * 512]); }
#define STAGE_V(kv0) {                                                \
    gload16(Vp + (size_t)(t >> 4) * S_ + (kv0) + (t & 15) * 8,        \
            &vls[w * 512]);                                           \
    gload16(Vp + (size_t)(32 + (t >> 4)) * S_ + (kv0) + (t & 15) * 8, \
            &vls[4096 + w * 512]); }

  for (int ci = 0; ci < 2; ++ci) {
    const int qc = ci ? (15 - pr) : pr;
    const int q0 = qc * 128;
    const int qrow = q0 + w * 16 + llo;
    bf16x8 aq0 = *(const bf16x8*)(Qp + (size_t)qrow * DH_ + lhi * 8);
    bf16x8 aq1 = *(const bf16x8*)(Qp + (size_t)qrow * DH_ + 32 + lhi * 8);
    const int n128 = qc + 1;

    __syncthreads();              // previous chunk's readers done
    STAGE_K(0, 0)
    STAGE_V(0)
    __syncthreads();              // drains vmcnt: tile 0 resident

    f32x4 o[4] = {};
    f32x4 osum = {};
    const int crow = q0 + w * 16 + lhi * 4;
    const int sw = (llo & 7) << 4;

    for (int tt = 0; tt < n128 - 1; ++tt) {
      const int kv0 = tt << 7;
      const int cur = tt & 1;

      // ---- QK^T from kls[cur] (swizzled ds_read_b128, conflict-free) ----
      f32x4 sc[8] = {};
      __builtin_amdgcn_s_setprio(1);
#pragma unroll
      for (int f = 0; f < 8; ++f) {
        const char* base = (const char*)&kls[cur][0] + (f * 16 + llo) * 128;
        bf16x8 bk0 = *(const bf16x8*)(base + ((lhi * 16) ^ sw));
        bf16x8 bk1 = *(const bf16x8*)(base + ((64 + lhi * 16) ^ sw));
        sc[f] = __builtin_amdgcn_mfma_f32_16x16x32_bf16(aq0, bk0, sc[f], 0, 0, 0);
        sc[f] = __builtin_amdgcn_mfma_f32_16x16x32_bf16(aq1, bk1, sc[f], 0, 0, 0);
      }
      __builtin_amdgcn_s_setprio(0);

      // K[t+1] direct-to-LDS now: covered by softmax+PV
      STAGE_K(cur ^ 1, kv0 + 128)

      // ---- softmax numerator (unmasked main loop) ----
#pragma unroll
      for (int r = 0; r < 4; ++r) {
        float p[8];
#pragma unroll
        for (int f = 0; f < 8; ++f) p[f] = fexp2(sc[f][r]);
        u32x4 pw;
        pw[0] = cvt_pk_bf16(p[0], p[1]);
        pw[1] = cvt_pk_bf16(p[2], p[3]);
        pw[2] = cvt_pk_bf16(p[4], p[5]);
        pw[3] = cvt_pk_bf16(p[6], p[7]);
        const int row = lhi * 4 + r;
        *(u32x4*)((char*)&pl[w][0][0] + row * 256 + ((llo * 16) ^ ((row & 7) << 4))) = pw;
      }

      // ---- PV + row-sum (XOR'd conflict-free V reads) ----
      __builtin_amdgcn_s_setprio(1);
#pragma unroll
      for (int kk = 0; kk < 4; ++kk) {
        bf16x8 ap = *(const bf16x8*)((const char*)&pl[w][0][0] + llo * 256 +
                                     ((kk * 64 + lhi * 16) ^ ((llo & 7) << 4)));
#pragma unroll
        for (int f = 0; f < 4; ++f) {
          const char* vbase = (const char*)vls + (f * 16 + llo) * 256;
          bf16x8 bv = *(const bf16x8*)(vbase + ((kk * 64 + lhi * 16) ^ (llo << 4)));
          o[f] = __builtin_amdgcn_mfma_f32_16x16x32_bf16(ap, bv, o[f], 0, 0, 0);
        }
        osum = __builtin_amdgcn_mfma_f32_16x16x32_bf16(ap, ones, osum, 0, 0, 0);
      }
      __builtin_amdgcn_s_setprio(0);

      __syncthreads();            // all V reads of this tile done
      STAGE_V(kv0 + 128)
      __syncthreads();            // drains vmcnt: K[t+1], V[t+1] resident
    }

    { // ---- diagonal tile (masked), no staging ----
      const int kv0 = (n128 - 1) << 7;
      const int cur = (n128 - 1) & 1;
      f32x4 sc[8] = {};
      __builtin_amdgcn_s_setprio(1);
#pragma unroll
      for (int f = 0; f < 8; ++f) {
        const char* base = (const char*)&kls[cur][0] + (f * 16 + llo) * 128;
        bf16x8 bk0 = *(const bf16x8*)(base + ((lhi * 16) ^ sw));
        bf16x8 bk1 = *(const bf16x8*)(base + ((64 + lhi * 16) ^ sw));
        sc[f] = __builtin_amdgcn_mfma_f32_16x16x32_bf16(aq0, bk0, sc[f], 0, 0, 0);
        sc[f] = __builtin_amdgcn_mfma_f32_16x16x32_bf16(aq1, bk1, sc[f], 0, 0, 0);
      }
      __builtin_amdgcn_s_setprio(0);

#pragma unroll
      for (int r = 0; r < 4; ++r) {
        float p[8];
#pragma unroll
        for (int f = 0; f < 8; ++f) {
          float x = sc[f][r];
          if (kv0 + f * 16 + llo > crow + r) x = -1e30f;
          p[f] = fexp2(x);
        }
        u32x4 pw;
        pw[0] = cvt_pk_bf16(p[0], p[1]);
        pw[1] = cvt_pk_bf16(p[2], p[3]);
        pw[2] = cvt_pk_bf16(p[4], p[5]);
        pw[3] = cvt_pk_bf16(p[6], p[7]);
        const int row = lhi * 4 + r;
        *(u32x4*)((char*)&pl[w][0][0] + row * 256 + ((llo * 16) ^ ((row & 7) << 4))) = pw;
      }

      __builtin_amdgcn_s_setprio(1);
#pragma unroll
      for (int kk = 0; kk < 4; ++kk) {
        bf16x8 ap = *(const bf16x8*)((const char*)&pl[w][0][0] + llo * 256 +
                                     ((kk * 64 + lhi * 16) ^ ((llo & 7) << 4)));
#pragma unroll
        for (int f = 0; f < 4; ++f) {
          const char* vbase = (const char*)vls + (f * 16 + llo) * 256;
          bf16x8 bv = *(const bf16x8*)(vbase + ((kk * 64 + lhi * 16) ^ (llo << 4)));
          o[f] = __builtin_amdgcn_mfma_f32_16x16x32_bf16(ap, bv, o[f], 0, 0, 0);
        }
        osum = __builtin_amdgcn_mfma_f32_16x16x32_bf16(ap, ones, osum, 0, 0, 0);
      }
      __builtin_amdgcn_s_setprio(0);
    }

    // ---- normalize + write merged-head layout ----
#pragma unroll
    for (int f = 0; f < 4; ++f)
#pragma unroll
      for (int r = 0; r < 4; ++r) {
        int row = crow + r;
        int dh = f * 16 + llo;
        float val = o[f][r] / osum[r];
        AO[((size_t)bb * S_ + row) * D_ + hh * DH_ + dh] = f2b(val);
      }
  }
#undef STAGE_K
#undef STAGE_V
}

extern "C" void kernel_launch(void* const* d_in, const int* in_sizes, int n_in,
                              void* d_out, int out_size, void* d_ws, size_t ws_size,
                              hipStream_t stream) {
  const float* x  = (const float*)d_in[0];
  const float* w1 = (const float*)d_in[1];
  const float* b1 = (const float*)d_in[2];
  const float* w2 = (const float*)d_in[3];
  const float* b2 = (const float*)d_in[4];
  float* out = (float*)d_out;
  char* ws = (char*)d_ws;

  u16* xb  = (u16*)(ws);                 // 16 MB (reused as AO after gemm1)
  u16* w1t = (u16*)(ws + 16777216);      // 6 MB
  u16* w2t = (u16*)(ws + 23068672);      // 2 MB
  u16* qb  = (u16*)(ws + 25165824);      // 16 MB
  u16* kb  = (u16*)(ws + 41943040);      // 16 MB
  u16* vtb = (u16*)(ws + 58720256);      // 16 MB
  u16* ao  = xb;

  prep_fused<<<6144, 256, 0, stream>>>(x, xb, w1, w1t, w2, w2t);

  gemm_bt<1><<<dim3(24, 64), 256, 0, stream>>>(xb, w1t, b1, nullptr, qb, kb, vtb, 3072, 1024);
  repack_v<<<4096, 256, 0, stream>>>(vtb);
  attn128<<<dim3(8, 64), 512, 0, stream>>>(qb, kb, vtb, ao);
  gemm_bt<0><<<dim3(8, 64), 256, 0, stream>>>(ao, w2t, b2, out, nullptr, nullptr, nullptr, 1024, 1024);
}

// Round 23
// 158.954 us; speedup vs baseline: 1.1442x; 1.1442x over previous
//
#include <hip/hip_runtime.h>

typedef unsigned short u16;
typedef short bf16x8 __attribute__((ext_vector_type(8)));
typedef float f32x4 __attribute__((ext_vector_type(4)));
typedef unsigned int u32;
typedef u32 u32x4 __attribute__((ext_vector_type(4)));

#define B_ 4
#define S_ 2048
#define D_ 1024
#define H_ 16
#define DH_ 64
#define M_ 8192   // B*S
#define SCL2E 0.1803368801111244f  /* 0.125 * log2(e), folded into Q at gemm1 */

__device__ __forceinline__ u16 f2b(float f) {
  union { float f; unsigned int u; } v; v.f = f;
  unsigned int u = v.u;
  unsigned int r = (u + 0x7FFFu + ((u >> 16) & 1u)) >> 16;
  return (u16)r;
}

// async global->LDS, 16B per lane; lds dst is wave-uniform base + lane*16
// (SOURCE address is per-lane — swizzles go on the source side)
__device__ __forceinline__ void gload16(const void* g, void* l) {
  __builtin_amdgcn_global_load_lds(
      (const __attribute__((address_space(1))) unsigned int*)g,
      (__attribute__((address_space(3))) unsigned int*)l,
      16, 0, 0);
}

// pack two f32 -> two bf16 (RNE) in one VALU op
__device__ __forceinline__ u32 cvt_pk_bf16(float lo, float hi) {
  u32 r;
  asm("v_cvt_pk_bf16_f32 %0, %1, %2" : "=v"(r) : "v"(lo), "v"(hi));
  return r;
}

// exp2 as a single v_exp_f32
__device__ __forceinline__ float fexp2(float x) {
  float r;
  asm("v_exp_f32 %0, %1" : "=v"(r) : "v"(x));
  return r;
}

// ---------------- fused preprocessing: one kernel, three block ranges ----------------
struct __attribute__((aligned(8))) u16x4 { u16 x, y, z, w; };

__global__ __launch_bounds__(256) void prep_fused(
    const float* __restrict__ x, u16* __restrict__ xb,
    const float* __restrict__ w1, u16* __restrict__ w1t,
    const float* __restrict__ w2, u16* __restrict__ w2t) {
  __shared__ float tile[32][33];
  const int bid = blockIdx.x, t = threadIdx.x;

  if (bid < 2048) {
    const int n = M_ * D_;
    for (int i = (bid * 256 + t) * 4; i < n; i += 2048 * 256 * 4) {
      float4 v = *(const float4*)(x + i);
      u16x4 o; o.x = f2b(v.x); o.y = f2b(v.y); o.z = f2b(v.z); o.w = f2b(v.w);
      *(u16x4*)(xb + i) = o;
    }
    return;
  }

  const float* in;  u16* outp;  int R, C, bx, by;
  if (bid < 5120) {
    int rel = bid - 2048; bx = rel % 96; by = rel / 96;
    in = w1; outp = w1t; R = 1024; C = 3072;
  } else {
    int rel = bid - 5120; bx = rel % 32; by = rel / 32;
    in = w2; outp = w2t; R = 1024; C = 1024;
  }
  const int c0 = bx * 32, r0 = by * 32;
  const int tx = t & 31, ty = t >> 5;   // 32 x 8
#pragma unroll
  for (int j = 0; j < 32; j += 8)
    tile[ty + j][tx] = in[(size_t)(r0 + ty + j) * C + c0 + tx];
  __syncthreads();
#pragma unroll
  for (int j = 0; j < 32; j += 8)
    outp[(size_t)(c0 + ty + j) * R + r0 + tx] = f2b(tile[tx][ty + j]);
}

// ---------------- bf16 GEMM: A[M][K] @ BT[N][K]^T + bias (r12/r20 proven) ----------------
// 4-wave 128x128, BK=64, LDS double-buffered, counted vmcnt.
// MODE 0: fp32 out. MODE 1: qkv scatter — Q pre-scaled; K pre-swizzled
// (dh' = dh ^ ((s&7)<<3), free for gemm1); V^T slot-permuted ONLY (fast store;
// attn applies the dh-XOR via per-lane source addressing in STAGE_V).
template <int MODE>
__global__ __launch_bounds__(256) void gemm_bt(
    const u16* __restrict__ A, const u16* __restrict__ BT,
    const float* __restrict__ bias, float* __restrict__ outf,
    u16* __restrict__ qb, u16* __restrict__ kb, u16* __restrict__ vtb,
    int Ncols, int Kdim) {
  __shared__ __attribute__((aligned(16))) u16 lsA[2][128 * 64];
  __shared__ __attribute__((aligned(16))) u16 lsB[2][128 * 64];
  const int t = threadIdx.x;
  const int lane = t & 63, w = t >> 6;
  const int lhi = lane >> 4, llo = lane & 15;

  const int gx = gridDim.x;
  const int lin = blockIdx.y * gx + blockIdx.x;
  const int nwg = gx * gridDim.y;
  const int sw = (lin & 7) * (nwg >> 3) + (lin >> 3);
  const int m0 = (sw / gx) * 128, n0 = (sw % gx) * 128;

  const int wr = (w >> 1) * 64, wc = (w & 1) * 64;

  const int r8 = lane >> 3;
  const int scolE = ((lane & 7) ^ r8) * 8;
  const int srow = w * 32 + r8;

  f32x4 acc[4][4] = {};
  const int nt = Kdim >> 6;

#define STAGE_G(buf, kk0)                                                        \
  _Pragma("unroll") for (int j = 0; j < 4; ++j) {                                \
    gload16(A + (size_t)(m0 + srow + j * 8) * Kdim + (kk0) + scolE,              \
            &lsA[buf][(w * 32 + j * 8) * 64]);                                   \
    gload16(BT + (size_t)(n0 + srow + j * 8) * Kdim + (kk0) + scolE,             \
            &lsB[buf][(w * 32 + j * 8) * 64]);                                   \
  }

  STAGE_G(0, 0)

  for (int tt = 0; tt < nt; ++tt) {
    const int cur = tt & 1;
    if (tt + 1 < nt) {
      STAGE_G(cur ^ 1, (tt + 1) << 6)
      asm volatile("s_waitcnt vmcnt(8)" ::: "memory");
    } else {
      asm volatile("s_waitcnt vmcnt(0)" ::: "memory");
    }
    __builtin_amdgcn_sched_barrier(0);
    __builtin_amdgcn_s_barrier();
    __builtin_amdgcn_sched_barrier(0);
#pragma unroll
    for (int kk = 0; kk < 2; ++kk) {
      bf16x8 af[4], bfr[4];
#pragma unroll
      for (int i = 0; i < 4; ++i) {
        int ra = wr + i * 16 + llo;
        af[i] = *(const bf16x8*)((const char*)&lsA[cur][ra * 64] +
                                 ((kk * 64 + lhi * 16) ^ ((ra & 7) << 4)));
        int rb = wc + i * 16 + llo;
        bfr[i] = *(const bf16x8*)((const char*)&lsB[cur][rb * 64] +
                                  ((kk * 64 + lhi * 16) ^ ((rb & 7) << 4)));
      }
#pragma unroll
      for (int mi = 0; mi < 4; ++mi)
#pragma unroll
        for (int ni = 0; ni < 4; ++ni)
          acc[mi][ni] = __builtin_amdgcn_mfma_f32_16x16x32_bf16(af[mi], bfr[ni], acc[mi][ni], 0, 0, 0);
    }
    __builtin_amdgcn_sched_barrier(0);
    __builtin_amdgcn_s_barrier();
  }
#undef STAGE_G

  if (MODE == 0) {
#pragma unroll
    for (int mi = 0; mi < 4; ++mi)
#pragma unroll
      for (int ni = 0; ni < 4; ++ni)
#pragma unroll
        for (int r = 0; r < 4; ++r) {
          int m = m0 + wr + mi * 16 + lhi * 4 + r;
          int n = n0 + wc + ni * 16 + llo;
          outf[(size_t)m * Ncols + n] = acc[mi][ni][r] + bias[n];
        }
  } else if (n0 < 1024) {            // Q (pre-scaled)
#pragma unroll
    for (int mi = 0; mi < 4; ++mi)
#pragma unroll
      for (int ni = 0; ni < 4; ++ni)
#pragma unroll
        for (int r = 0; r < 4; ++r) {
          int m = m0 + wr + mi * 16 + lhi * 4 + r;
          int n = n0 + wc + ni * 16 + llo;
          int bidx = m >> 11, s = m & 2047, hh = n >> 6, dh = n & 63;
          qb[((size_t)(bidx * 16 + hh) * 2048 + s) * 64 + dh] =
              f2b((acc[mi][ni][r] + bias[n]) * SCL2E);
        }
  } else if (n0 < 2048) {            // K, pre-swizzled for attn direct gload
#pragma unroll
    for (int mi = 0; mi < 4; ++mi)
#pragma unroll
      for (int ni = 0; ni < 4; ++ni)
#pragma unroll
        for (int r = 0; r < 4; ++r) {
          int m = m0 + wr + mi * 16 + lhi * 4 + r;
          int n2 = n0 - 1024 + wc + ni * 16 + llo;
          int bidx = m >> 11, s = m & 2047, hh = n2 >> 6;
          int dh = (n2 & 63) ^ ((s & 7) << 3);
          kb[((size_t)(bidx * 16 + hh) * 2048 + s) * 64 + dh] =
              f2b(acc[mi][ni][r] + bias[n0 + wc + ni * 16 + llo]);
        }
  } else {                           // V^T, slot-permuted ONLY (fast store)
#pragma unroll
    for (int mi = 0; mi < 4; ++mi)
#pragma unroll
      for (int ni = 0; ni < 4; ++ni)
#pragma unroll
        for (int r = 0; r < 4; ++r) {
          int m = m0 + wr + mi * 16 + lhi * 4 + r;
          int n2 = n0 - 2048 + wc + ni * 16 + llo;
          int bidx = m >> 11, s = m & 2047, hh = n2 >> 6, dh = n2 & 63;
          int col = (s & ~127) | ((s & 15) * 8 + ((s >> 4) & 7));
          vtb[((size_t)(bidx * 16 + hh) * 64 + dh) * 2048 + col] =
              f2b(acc[mi][ni][r] + bias[n0 + wc + ni * 16 + llo]);
        }
  }
}

// ---------------- flash-style causal attention, 8-wave blocks (r20 best config) ----------------
// K double-buffered + V single-buffered, BOTH staged direct via global_load_lds.
// K global pre-swizzled by gemm1; V's dh-XOR applied via PER-LANE SOURCE address
// in STAGE_V (chunk g of row r reads global chunk g^(r&15) — same 256B windows,
// identical coalescing, LDS content identical to the repacked version).
// XOR'd conflict-free reads. P unpadded row-XOR. exp2 via v_exp_f32; row-sum
// via ones-MFMA. LDS = 32(K dbuf) + 16(V) + 32(P) = 80 KB -> 2 blocks/CU.
__global__ __launch_bounds__(512) void attn128(
    const u16* __restrict__ Qb, const u16* __restrict__ Kb,
    const u16* __restrict__ VTb, u16* __restrict__ AO) {
  __shared__ __attribute__((aligned(16))) u16 kls[2][128 * 64]; // K tiles (dbuf)
  __shared__ __attribute__((aligned(16))) u16 vls[64 * 128];    // V^T tile
  __shared__ __attribute__((aligned(16))) u16 pl[8][16][128];   // P, row-XOR swizzled
  const int t = threadIdx.x, w = t >> 6, lane = t & 63;
  const int lhi = lane >> 4, llo = lane & 15;

  // XCD-grouping swizzle (bijective): all 8 pr-blocks of a head share one XCD
  const int lin = blockIdx.y * 8 + blockIdx.x;
  const int bh = ((lin >> 6) << 3) | (lin & 7);
  const int pr = (lin >> 3) & 7;
  const int bb = bh >> 4, hh = bh & 15;

  const u16* Qp = Qb + (size_t)bh * (S_ * DH_);
  const u16* Kp = Kb + (size_t)bh * (S_ * DH_);
  const u16* Vp = VTb + (size_t)bh * (DH_ * S_);

  bf16x8 ones;
#pragma unroll
  for (int i = 0; i < 8; ++i) ones[i] = (short)0x3F80;

#define STAGE_K(buf, kv0) {                                           \
    const u16* s_ = Kp + (size_t)(kv0) * 64 + t * 8;                  \
    gload16(s_,        &kls[buf][w * 512]);                           \
    gload16(s_ + 4096, &kls[buf][4096 + w * 512]); }
  // V: dh-XOR on the per-lane SOURCE address (LDS dest stays linear)
#define STAGE_V(kv0) {                                                \
    const int vr0 = t >> 4;                                           \
    const int vcE = (((t & 15) ^ (vr0 & 15)) * 8);                    \
    gload16(Vp + (size_t)vr0 * S_ + (kv0) + vcE, &vls[w * 512]);      \
    gload16(Vp + (size_t)(32 + vr0) * S_ + (kv0) + vcE,               \
            &vls[4096 + w * 512]); }

  for (int ci = 0; ci < 2; ++ci) {
    const int qc = ci ? (15 - pr) : pr;
    const int q0 = qc * 128;
    const int qrow = q0 + w * 16 + llo;
    bf16x8 aq0 = *(const bf16x8*)(Qp + (size_t)qrow * DH_ + lhi * 8);
    bf16x8 aq1 = *(const bf16x8*)(Qp + (size_t)qrow * DH_ + 32 + lhi * 8);
    const int n128 = qc + 1;

    __syncthreads();              // previous chunk's readers done
    STAGE_K(0, 0)
    STAGE_V(0)
    __syncthreads();              // drains vmcnt: tile 0 resident

    f32x4 o[4] = {};
    f32x4 osum = {};
    const int crow = q0 + w * 16 + lhi * 4;
    const int sw = (llo & 7) << 4;

    for (int tt = 0; tt < n128 - 1; ++tt) {
      const int kv0 = tt << 7;
      const int cur = tt & 1;

      // ---- QK^T from kls[cur] (swizzled ds_read_b128, conflict-free) ----
      f32x4 sc[8] = {};
      __builtin_amdgcn_s_setprio(1);
#pragma unroll
      for (int f = 0; f < 8; ++f) {
        const char* base = (const char*)&kls[cur][0] + (f * 16 + llo) * 128;
        bf16x8 bk0 = *(const bf16x8*)(base + ((lhi * 16) ^ sw));
        bf16x8 bk1 = *(const bf16x8*)(base + ((64 + lhi * 16) ^ sw));
        sc[f] = __builtin_amdgcn_mfma_f32_16x16x32_bf16(aq0, bk0, sc[f], 0, 0, 0);
        sc[f] = __builtin_amdgcn_mfma_f32_16x16x32_bf16(aq1, bk1, sc[f], 0, 0, 0);
      }
      __builtin_amdgcn_s_setprio(0);

      // K[t+1] direct-to-LDS now: covered by softmax+PV
      STAGE_K(cur ^ 1, kv0 + 128)

      // ---- softmax numerator (unmasked main loop) ----
#pragma unroll
      for (int r = 0; r < 4; ++r) {
        float p[8];
#pragma unroll
        for (int f = 0; f < 8; ++f) p[f] = fexp2(sc[f][r]);
        u32x4 pw;
        pw[0] = cvt_pk_bf16(p[0], p[1]);
        pw[1] = cvt_pk_bf16(p[2], p[3]);
        pw[2] = cvt_pk_bf16(p[4], p[5]);
        pw[3] = cvt_pk_bf16(p[6], p[7]);
        const int row = lhi * 4 + r;
        *(u32x4*)((char*)&pl[w][0][0] + row * 256 + ((llo * 16) ^ ((row & 7) << 4))) = pw;
      }

      // ---- PV + row-sum (XOR'd conflict-free V reads) ----
      __builtin_amdgcn_s_setprio(1);
#pragma unroll
      for (int kk = 0; kk < 4; ++kk) {
        bf16x8 ap = *(const bf16x8*)((const char*)&pl[w][0][0] + llo * 256 +
                                     ((kk * 64 + lhi * 16) ^ ((llo & 7) << 4)));
#pragma unroll
        for (int f = 0; f < 4; ++f) {
          const char* vbase = (const char*)vls + (f * 16 + llo) * 256;
          bf16x8 bv = *(const bf16x8*)(vbase + ((kk * 64 + lhi * 16) ^ (llo << 4)));
          o[f] = __builtin_amdgcn_mfma_f32_16x16x32_bf16(ap, bv, o[f], 0, 0, 0);
        }
        osum = __builtin_amdgcn_mfma_f32_16x16x32_bf16(ap, ones, osum, 0, 0, 0);
      }
      __builtin_amdgcn_s_setprio(0);

      __syncthreads();            // all V reads of this tile done
      STAGE_V(kv0 + 128)
      __syncthreads();            // drains vmcnt: K[t+1], V[t+1] resident
    }

    { // ---- diagonal tile (masked), no staging ----
      const int kv0 = (n128 - 1) << 7;
      const int cur = (n128 - 1) & 1;
      f32x4 sc[8] = {};
      __builtin_amdgcn_s_setprio(1);
#pragma unroll
      for (int f = 0; f < 8; ++f) {
        const char* base = (const char*)&kls[cur][0] + (f * 16 + llo) * 128;
        bf16x8 bk0 = *(const bf16x8*)(base + ((lhi * 16) ^ sw));
        bf16x8 bk1 = *(const bf16x8*)(base + ((64 + lhi * 16) ^ sw));
        sc[f] = __builtin_amdgcn_mfma_f32_16x16x32_bf16(aq0, bk0, sc[f], 0, 0, 0);
        sc[f] = __builtin_amdgcn_mfma_f32_16x16x32_bf16(aq1, bk1, sc[f], 0, 0, 0);
      }
      __builtin_amdgcn_s_setprio(0);

#pragma unroll
      for (int r = 0; r < 4; ++r) {
        float p[8];
#pragma unroll
        for (int f = 0; f < 8; ++f) {
          float x = sc[f][r];
          if (kv0 + f * 16 + llo > crow + r) x = -1e30f;
          p[f] = fexp2(x);
        }
        u32x4 pw;
        pw[0] = cvt_pk_bf16(p[0], p[1]);
        pw[1] = cvt_pk_bf16(p[2], p[3]);
        pw[2] = cvt_pk_bf16(p[4], p[5]);
        pw[3] = cvt_pk_bf16(p[6], p[7]);
        const int row = lhi * 4 + r;
        *(u32x4*)((char*)&pl[w][0][0] + row * 256 + ((llo * 16) ^ ((row & 7) << 4))) = pw;
      }

      __builtin_amdgcn_s_setprio(1);
#pragma unroll
      for (int kk = 0; kk < 4; ++kk) {
        bf16x8 ap = *(const bf16x8*)((const char*)&pl[w][0][0] + llo * 256 +
                                     ((kk * 64 + lhi * 16) ^ ((llo & 7) << 4)));
#pragma unroll
        for (int f = 0; f < 4; ++f) {
          const char* vbase = (const char*)vls + (f * 16 + llo) * 256;
          bf16x8 bv = *(const bf16x8*)(vbase + ((kk * 64 + lhi * 16) ^ (llo << 4)));
          o[f] = __builtin_amdgcn_mfma_f32_16x16x32_bf16(ap, bv, o[f], 0, 0, 0);
        }
        osum = __builtin_amdgcn_mfma_f32_16x16x32_bf16(ap, ones, osum, 0, 0, 0);
      }
      __builtin_amdgcn_s_setprio(0);
    }

    // ---- normalize + write merged-head layout ----
#pragma unroll
    for (int f = 0; f < 4; ++f)
#pragma unroll
      for (int r = 0; r < 4; ++r) {
        int row = crow + r;
        int dh = f * 16 + llo;
        float val = o[f][r] / osum[r];
        AO[((size_t)bb * S_ + row) * D_ + hh * DH_ + dh] = f2b(val);
      }
  }
#undef STAGE_K
#undef STAGE_V
}

extern "C" void kernel_launch(void* const* d_in, const int* in_sizes, int n_in,
                              void* d_out, int out_size, void* d_ws, size_t ws_size,
                              hipStream_t stream) {
  const float* x  = (const float*)d_in[0];
  const float* w1 = (const float*)d_in[1];
  const float* b1 = (const float*)d_in[2];
  const float* w2 = (const float*)d_in[3];
  const float* b2 = (const float*)d_in[4];
  float* out = (float*)d_out;
  char* ws = (char*)d_ws;

  u16* xb  = (u16*)(ws);                 // 16 MB (reused as AO after gemm1)
  u16* w1t = (u16*)(ws + 16777216);      // 6 MB
  u16* w2t = (u16*)(ws + 23068672);      // 2 MB
  u16* qb  = (u16*)(ws + 25165824);      // 16 MB
  u16* kb  = (u16*)(ws + 41943040);      // 16 MB
  u16* vtb = (u16*)(ws + 58720256);      // 16 MB
  u16* ao  = xb;

  prep_fused<<<6144, 256, 0, stream>>>(x, xb, w1, w1t, w2, w2t);

  gemm_bt<1><<<dim3(24, 64), 256, 0, stream>>>(xb, w1t, b1, nullptr, qb, kb, vtb, 3072, 1024);
  attn128<<<dim3(8, 64), 512, 0, stream>>>(qb, kb, vtb, ao);
  gemm_bt<0><<<dim3(8, 64), 256, 0, stream>>>(ao, w2t, b2, out, nullptr, nullptr, nullptr, 1024, 1024);
}